// Round 3
// baseline (151.421 us; speedup 1.0000x reference)
//
#include <hip/hip_runtime.h>

// SparseMatmul3D: out[b,n,m] = sum_k x[b,n,k] * y[b,m,k]
// B=4, N=M=4096, D=64, fp32 in/out. Write-bound (268 MB out, floor ~38us).
// R1: direct 64B-segment stores            -> 89.7 us (~3 TB/s write)
// R2: LDS-staged full-line stores          -> 94.5 us (segmentation NOT the issue)
// R3: slab tiling: 32 rows x full 4096-m per block, each output row written
//     in ascending order by one block -> long sequential write streams.

#define BATCH 4
#define NN 4096
#define MM 4096
#define DD 64

typedef __attribute__((ext_vector_type(8))) short bf16x8;
typedef __attribute__((ext_vector_type(4))) float f32x4;
typedef __attribute__((ext_vector_type(4))) unsigned u32x4;

__device__ __forceinline__ unsigned cvt_pk_bf16(float lo, float hi) {
    unsigned r;
    asm("v_cvt_pk_bf16_f32 %0, %1, %2" : "=v"(r) : "v"(lo), "v"(hi));
    return r;
}

__device__ __forceinline__ bf16x8 load8_bf16(const float* __restrict__ p) {
    f32x4 v0 = *reinterpret_cast<const f32x4*>(p);
    f32x4 v1 = *reinterpret_cast<const f32x4*>(p + 4);
    u32x4 u = (u32x4){cvt_pk_bf16(v0[0], v0[1]), cvt_pk_bf16(v0[2], v0[3]),
                      cvt_pk_bf16(v1[0], v1[1]), cvt_pk_bf16(v1[2], v1[3])};
    return __builtin_bit_cast(bf16x8, u);
}

__global__ __launch_bounds__(256, 2) void
SparseMatmul3D_36155034698289_kernel(const float* __restrict__ x,
                                     const float* __restrict__ y,
                                     float* __restrict__ out) {
    const int bid    = blockIdx.x;                     // [0,512)
    const int b      = (bid & 7) >> 1;                 // 2 XCDs per batch
    const int nchunk = ((bid >> 3) << 1) | (bid & 1);  // [0,128)
    const int n0     = nchunk * 32;

    const int lane  = threadIdx.x & 63;
    const int w     = threadIdx.x >> 6;   // 4 waves: 2 n-subtiles x 2 m-halves
    const int wn    = (w & 1) * 16;
    const int wmh   = (w >> 1) * 128;     // m-half within each 256-wide chunk
    const int row16 = lane & 15;
    const int kgrp  = lane >> 4;

    const float* __restrict__ xb = x + (size_t)b * NN * DD;
    const float* __restrict__ yb = y + (size_t)b * MM * DD;

    // B operand = x rows (n side), resident in registers for the whole block
    bf16x8 bfrag[2];
    {
        const float* p = xb + (size_t)(n0 + wn + row16) * DD + kgrp * 8;
        bfrag[0] = load8_bf16(p);
        bfrag[1] = load8_bf16(p + 32);
    }

    const int n = n0 + wn + row16;        // this lane's output row (col of D)
    float* __restrict__ orow = out + (size_t)b * NN * MM + (size_t)n * MM;
    const float* __restrict__ ybase = yb + (size_t)(wmh + row16) * DD + kgrp * 8;

    // Walk m left->right: 16 chunks of 256 (this wave covers 128 of each).
#pragma unroll 2
    for (int mc = 0; mc < 16; ++mc) {
        const float* yp = ybase + (size_t)mc * 256 * DD;

        bf16x8 af[8][2];                  // A operand = y rows (m side)
#pragma unroll
        for (int mt = 0; mt < 8; ++mt) {
            af[mt][0] = load8_bf16(yp + (size_t)mt * 16 * DD);
            af[mt][1] = load8_bf16(yp + (size_t)mt * 16 * DD + 32);
        }

        f32x4 acc[8];
#pragma unroll
        for (int mt = 0; mt < 8; ++mt) acc[mt] = (f32x4){0.f, 0.f, 0.f, 0.f};

#pragma unroll
        for (int ks = 0; ks < 2; ++ks)
#pragma unroll
            for (int mt = 0; mt < 8; ++mt)
                acc[mt] = __builtin_amdgcn_mfma_f32_16x16x32_bf16(
                    af[mt][ks], bfrag[ks], acc[mt], 0, 0, 0);

        // D layout: col = lane&15 = n; row = kgrp*4+reg = m (4 consecutive m)
        const int mbase = mc * 256 + wmh + kgrp * 4;
#pragma unroll
        for (int mt = 0; mt < 8; ++mt)
            *reinterpret_cast<f32x4*>(orow + mbase + mt * 16) = acc[mt];
    }
}

extern "C" void kernel_launch(void* const* d_in, const int* in_sizes, int n_in,
                              void* d_out, int out_size, void* d_ws, size_t ws_size,
                              hipStream_t stream) {
    const float* x = (const float*)d_in[0];
    const float* y = (const float*)d_in[1];
    float* out = (float*)d_out;

    dim3 grid(512);
    dim3 block(256);
    SparseMatmul3D_36155034698289_kernel<<<grid, block, 0, stream>>>(x, y, out);
}

// Round 5
// 132.448 us; speedup vs baseline: 1.1432x; 1.1432x over previous
//
#include <hip/hip_runtime.h>

// SparseMatmul3D: out[b,n,m] = sum_k x[b,n,k] * y[b,m,k]
// B=4, N=M=4096, D=64, fp32 in/out. Write-bound (268 MB out, floor ~38us @7TB/s).
// R1: direct 64B-segment stores, 4096 blocks      -> 89.7 us (~3.0 TB/s)
// R2: LDS-staged full-line stores                 -> 94.5 us (segmentation not it)
// R3: 32-row slabs, 512 blocks, lockstep m-walk   -> 163 us (1.6 TB/s: channel
//     imbalance — all blocks writing same intra-row offset band simultaneously)
// R4: + stagger, cvt_pk asm, launch_bounds(,4)    -> NaN (suspect asm miscompile
//     under tightened regalloc; algorithm audited clean)
// R5: R4 structure, asm removed (pure-C f2bf, proven R1/R2), no unroll pragma.

#define BATCH 4
#define NN 4096
#define MM 4096
#define DD 64

typedef __attribute__((ext_vector_type(8))) short bf16x8;
typedef __attribute__((ext_vector_type(4))) float f32x4;

__device__ __forceinline__ unsigned short f2bf(float f) {
    unsigned u = __builtin_bit_cast(unsigned, f);
    u += 0x7FFFu + ((u >> 16) & 1u);   // round-to-nearest-even
    return (unsigned short)(u >> 16);
}

__device__ __forceinline__ bf16x8 load8_bf16(const float* __restrict__ p) {
    f32x4 v0 = *reinterpret_cast<const f32x4*>(p);
    f32x4 v1 = *reinterpret_cast<const f32x4*>(p + 4);
    bf16x8 r;
    r[0] = (short)f2bf(v0[0]); r[1] = (short)f2bf(v0[1]);
    r[2] = (short)f2bf(v0[2]); r[3] = (short)f2bf(v0[3]);
    r[4] = (short)f2bf(v1[0]); r[5] = (short)f2bf(v1[1]);
    r[6] = (short)f2bf(v1[2]); r[7] = (short)f2bf(v1[3]);
    return r;
}

__global__ __launch_bounds__(256, 4) void
SparseMatmul3D_36155034698289_kernel(const float* __restrict__ x,
                                     const float* __restrict__ y,
                                     float* __restrict__ out) {
    const int bid   = blockIdx.x;                     // [0,1024)
    const int b     = (bid & 7) >> 1;                 // 2 XCDs per batch
    const int s     = ((bid >> 3) << 1) | (bid & 1);  // slab [0,256)
    const int n0    = s * 16;
    const int phase = (bid >> 3) & 15;                // anti-lockstep stagger

    const int lane  = threadIdx.x & 63;
    const int w     = threadIdx.x >> 6;   // 4 waves: m-quarter of each chunk
    const int wm    = w * 64;
    const int row16 = lane & 15;
    const int kgrp  = lane >> 4;

    const float* __restrict__ xb = x + (size_t)b * NN * DD;
    const float* __restrict__ yb = y + (size_t)b * MM * DD;

    // B operand = x rows (n side): one 16-row subtile, resident all kernel
    bf16x8 bfrag[2];
    {
        const float* p = xb + (size_t)(n0 + row16) * DD + kgrp * 8;
        bfrag[0] = load8_bf16(p);
        bfrag[1] = load8_bf16(p + 32);
    }

    const int n = n0 + row16;             // this lane's output row
    float* __restrict__ orow = out + (size_t)b * NN * MM + (size_t)n * MM;
    const float* __restrict__ ybase = yb + (size_t)(wm + row16) * DD + kgrp * 8;

    // Walk m in 16 chunks of 256 (this wave covers 64 of each), phase-staggered.
    for (int mcc = 0; mcc < 16; ++mcc) {
        const int mc = (mcc + phase) & 15;
        const float* yp = ybase + (size_t)mc * 256 * DD;

        bf16x8 af[4][2];                  // A operand = y rows (m side)
#pragma unroll
        for (int mt = 0; mt < 4; ++mt) {
            af[mt][0] = load8_bf16(yp + (size_t)mt * 16 * DD);
            af[mt][1] = load8_bf16(yp + (size_t)mt * 16 * DD + 32);
        }

        f32x4 acc[4];
#pragma unroll
        for (int mt = 0; mt < 4; ++mt) acc[mt] = (f32x4){0.f, 0.f, 0.f, 0.f};

#pragma unroll
        for (int ks = 0; ks < 2; ++ks)
#pragma unroll
            for (int mt = 0; mt < 4; ++mt)
                acc[mt] = __builtin_amdgcn_mfma_f32_16x16x32_bf16(
                    af[mt][ks], bfrag[ks], acc[mt], 0, 0, 0);

        // D layout: col = lane&15 = n; row = kgrp*4+reg = m (4 consecutive m)
        const int mbase = mc * 256 + wm + kgrp * 4;
#pragma unroll
        for (int mt = 0; mt < 4; ++mt)
            *reinterpret_cast<f32x4*>(orow + mbase + mt * 16) = acc[mt];
    }
}

extern "C" void kernel_launch(void* const* d_in, const int* in_sizes, int n_in,
                              void* d_out, int out_size, void* d_ws, size_t ws_size,
                              hipStream_t stream) {
    const float* x = (const float*)d_in[0];
    const float* y = (const float*)d_in[1];
    float* out = (float*)d_out;

    dim3 grid(1024);
    dim3 block(256);
    SparseMatmul3D_36155034698289_kernel<<<grid, block, 0, stream>>>(x, y, out);
}